// Round 12
// baseline (313.458 us; speedup 1.0000x reference)
//
#include <hip/hip_runtime.h>
#include <cmath>

#define B_ 4
#define S_ 2048
#define D_ 1024
#define H_ 16
#define HD_ 64

typedef __attribute__((ext_vector_type(8))) _Float16 half8;
typedef __attribute__((ext_vector_type(2))) _Float16 half2t;
typedef __attribute__((ext_vector_type(2))) __fp16 fp16x2;
typedef __attribute__((ext_vector_type(4))) float floatx4;
typedef __attribute__((ext_vector_type(16))) float floatx16;
typedef __attribute__((ext_vector_type(2))) unsigned uint2v;

// ---------------- fp16 helpers ----------------
union H2U { unsigned u; half2t h; fp16x2 f; };
__device__ __forceinline__ unsigned hpack2(float a, float b) {   // RNE
    H2U x; x.h[0] = (_Float16)a; x.h[1] = (_Float16)b; return x.u;
}
__device__ __forceinline__ unsigned pkrtz(float a, float b) {    // RTZ, 1 instr
    H2U x; x.f = __builtin_amdgcn_cvt_pkrtz(a, b); return x.u;
}
__device__ __forceinline__ float h_lo(unsigned u) { H2U x; x.u = u; return (float)x.h[0]; }
__device__ __forceinline__ float h_hi(unsigned u) { H2U x; x.u = u; return (float)x.h[1]; }

// barrier that waits LDS ops only — leaves global prefetch loads in flight
__device__ __forceinline__ void barrier_lgkm() {
    asm volatile("s_waitcnt lgkmcnt(0)\n\ts_barrier" ::: "memory");
}

// ---------------- merged prepass: weights + biases + RoPE table -------------
// (X conversion removed — gemm1 now reads X fp32 directly and converts in
// staging with the SAME hpack2 RNE -> bit-identical.)
// Blocks [0,2048): weights. Block 2048: biases. Blocks [2049,2305): RoPE
// table tab[s][d] = (sin(s*f_d), cos(s*f_d)), f_d = exp(-d*ln(10000)/32).
// Table precomputed here because libm sinf/cosf are real calls that force
// acc spills inside the GEMM (round-9 lesson).
__global__ __launch_bounds__(256)
void conv_all(const float* __restrict__ Wq, const float* __restrict__ Wk,
              const float* __restrict__ Wv, const float* __restrict__ Wo,
              const float* __restrict__ bq, const float* __restrict__ bk,
              const float* __restrict__ bv,
              unsigned short* __restrict__ Wqkvf, unsigned short* __restrict__ Wof,
              float* __restrict__ bqkv, float2* __restrict__ tab)
{
    const int t = threadIdx.x;
    const int bxx = blockIdx.x;
    if (bxx < 2048) {
        const int w = bxx >> 9;
        const int i = ((bxx & 511) * 256 + t) * 8;
        const float* src = (w == 0) ? Wq : (w == 1) ? Wk : (w == 2) ? Wv : Wo;
        const float4 a = *(const float4*)(src + i);
        const float4 b = *(const float4*)(src + i + 4);
        const uint4 v = make_uint4(hpack2(a.x, a.y), hpack2(a.z, a.w),
                                   hpack2(b.x, b.y), hpack2(b.z, b.w));
        if (w < 3)
            *(uint4*)(Wqkvf + (size_t)w * 1048576 + i) = v;
        else
            *(uint4*)(Wof + i) = v;
    } else if (bxx == 2048) {
        const int idx = t * 4;
        *(float4*)(bqkv + idx)        = *(const float4*)(bq + idx);
        *(float4*)(bqkv + 1024 + idx) = *(const float4*)(bk + idx);
        *(float4*)(bqkv + 2048 + idx) = *(const float4*)(bv + idx);
    } else {
        const int idx = (bxx - 2049) * 256 + t;   // [0, 65536): s*32 + d
        const int s = idx >> 5, d = idx & 31;
        const float kfreq = 0.28782313662425572f; // ln(10000)/32
        const float fd = expf(-(float)d * kfreq);
        const float tt = (float)s * fd;
        tab[idx] = make_float2(sinf(tt), cosf(tt));
    }
}

// ---------------- GEMM NT, fp16 reg-staged MFMA (round-2 core) --------------
// C[M,N] = A[M,K] * B[N,K]^T + bias. 128x128 tile, BK=32, 256 thr.
// Frag-ordered LDS with k-chunk XOR swizzle; register prefetch of tile k+1.
// MODE 0: A is fp16; fp32 out to C0.
// MODE 1: A is fp32 (X read directly — conversion via the same RNE hpack2 as
//   the old conv_x, so numerics are bit-identical; X is L3-resident so the 2x
//   A-bytes are cache-absorbed). Fused QKV epilogue: RoPE(Q,K) from table
//   (Q->C0, K->C1 scaled 0.125*log2e); V written directly transposed to
//   C2 = Vt (B,H,64,S) — one aligned 8B store per acc quad.
template<int MODE>
__global__ __launch_bounds__(256, 2)
void gemm_half(const void* __restrict__ Av, const unsigned short* __restrict__ Bp,
               const float* __restrict__ bias, void* __restrict__ C0,
               void* __restrict__ C1, void* __restrict__ C2,
               const float2* __restrict__ Tab,
               int M, int N, int K)
{
    __shared__ uint4 ASH[512];
    __shared__ uint4 BSH[512];

    const int tid = threadIdx.x;
    const int bm = blockIdx.x * 128;
    const int bn = blockIdx.y * 128;
    const int w = tid >> 6, l = tid & 63;
    const int wm = (w & 1) * 64, wn = (w >> 1) * 64;

    floatx4 acc[4][4];
#pragma unroll
    for (int i = 0; i < 4; ++i)
#pragma unroll
        for (int j = 0; j < 4; ++j)
#pragma unroll
            for (int r = 0; r < 4; ++r) acc[i][j][r] = 0.f;

    // staging: thread t -> row r = t>>1, k-chunks sc = (t&1)*2 + {0,1} (32B contig)
    const int r0 = tid >> 1, scb = (tid & 1) * 2;
    const size_t ga = (size_t)(bm + r0) * K + scb * 8;
    const size_t gb = (size_t)(bn + r0) * K + scb * 8;
    const int blk = r0 >> 4, r15 = r0 & 15;
    const int p1 = (scb << 4) + r15;
    const int f0a = (blk << 6) + (p1 ^ (scb << 1));              // frag for sck=scb
    const int f0b = (blk << 6) + ((p1 + 16) ^ ((scb + 1) << 1)); // frag for sck=scb+1

    const half8* pA = (const half8*)ASH;
    const half8* pB = (const half8*)BSH;
    const int lg = l ^ ((l >> 4) << 1);      // swizzled position for reads
    const int am = (wm >> 4) * 64 + lg;
    const int bnf = (wn >> 4) * 64 + lg;

    auto loadA = [&](int kn, uint4& A0, uint4& A1) {
        if (MODE == 1) {
            const float* Ap = (const float*)Av;
            const float4 a0 = *(const float4*)(Ap + ga + kn);
            const float4 a1 = *(const float4*)(Ap + ga + kn + 4);
            const float4 a2 = *(const float4*)(Ap + ga + kn + 8);
            const float4 a3 = *(const float4*)(Ap + ga + kn + 12);
            A0 = make_uint4(hpack2(a0.x, a0.y), hpack2(a0.z, a0.w),
                            hpack2(a1.x, a1.y), hpack2(a1.z, a1.w));
            A1 = make_uint4(hpack2(a2.x, a2.y), hpack2(a2.z, a2.w),
                            hpack2(a3.x, a3.y), hpack2(a3.z, a3.w));
        } else {
            const unsigned short* Ap = (const unsigned short*)Av;
            A0 = *(const uint4*)(Ap + ga + kn);
            A1 = *(const uint4*)(Ap + ga + kn + 8);
        }
    };

    // prefetch k-tile 0
    uint4 vA0, vA1;
    loadA(0, vA0, vA1);
    uint4 vB0 = *(const uint4*)(Bp + gb);
    uint4 vB1 = *(const uint4*)(Bp + gb + 8);

    for (int k0 = 0; k0 < K; k0 += 32) {
        __syncthreads();
        ASH[f0a] = vA0; ASH[f0b] = vA1;
        BSH[f0a] = vB0; BSH[f0b] = vB1;
        __syncthreads();

        const int kn = (k0 + 32 < K) ? k0 + 32 : k0;
        loadA(kn, vA0, vA1);
        vB0 = *(const uint4*)(Bp + gb + kn);
        vB1 = *(const uint4*)(Bp + gb + kn + 8);

        half8 a[4];
#pragma unroll
        for (int i = 0; i < 4; ++i) a[i] = pA[am + i * 64];
#pragma unroll
        for (int j = 0; j < 4; ++j) {
            const half8 b = pB[bnf + j * 64];
#pragma unroll
            for (int i = 0; i < 4; ++i)
                acc[i][j] = __builtin_amdgcn_mfma_f32_16x16x32_f16(a[i], b, acc[i][j], 0, 0, 0);
        }
    }

    // epilogue: C/D layout col=lane&15, row=(lane>>4)*4+reg
    const int cr = (l >> 4) << 2;
    const int cc = l & 15;

    if (MODE == 0) {
#pragma unroll
        for (int j = 0; j < 4; ++j) {
            const int col = bn + wn + j * 16 + cc;
            const float bv = bias[col];
#pragma unroll
            for (int i = 0; i < 4; ++i) {
                const int row = bm + wm + i * 16 + cr;
#pragma unroll
                for (int r = 0; r < 4; ++r) {
                    ((float*)C0)[(size_t)(row + r) * N + col] = acc[i][j][r] + bv;
                }
            }
        }
    } else {
        const int reg = bn >> 10;            // 0=Q, 1=K, 2=V (bn 128-aligned)
        if (reg < 2) {
            const float KSs = (reg == 1) ? 0.18033688011112042f : 1.0f;  // 0.125*log2e
            unsigned short* dst0 = (unsigned short*)((reg == 0) ? C0 : C1);
            const int hbase = (bn - (reg << 10)) + wn;   // h*64 within D
#pragma unroll
            for (int j = 0; j < 2; ++j) {
                const int d = j * 16 + cc;               // RoPE dim in [0,32)
                const float b1 = bias[bn + wn + j * 16 + cc];
                const float b2 = bias[bn + wn + j * 16 + cc + 32];
#pragma unroll
                for (int i = 0; i < 4; ++i) {
                    const int row0 = bm + wm + i * 16 + cr;
#pragma unroll
                    for (int r = 0; r < 4; ++r) {
                        const int row = row0 + r;
                        const int s = row & (S_ - 1);
                        const float2 sc2 = Tab[s * 32 + d];
                        const float sn = sc2.x, cs = sc2.y;
                        const float x1 = acc[i][j][r] + b1;
                        const float x2 = acc[i][j + 2][r] + b2;
                        // reference quirk: c=sin part, s=cos part
                        const float o1 = (x1 * sn - x2 * cs) * KSs;
                        const float o2 = (x2 * sn + x1 * cs) * KSs;
                        unsigned short* p = dst0 + (size_t)row * D_ + hbase + d;
                        p[0]  = (unsigned short)(hpack2(o1, o1) & 0xffffu);
                        p[32] = (unsigned short)(hpack2(o2, o2) & 0xffffu);
                    }
                }
            }
        } else {
            // V: write DIRECTLY TRANSPOSED to Vt (B,H,64,S). acc[i][j][0..3]
            // = 4 consecutive s at fixed d -> one aligned 8B store.
#pragma unroll
            for (int j = 0; j < 4; ++j) {
                const int col = bn + wn + j * 16 + cc;
                const float bv = bias[col];
                const int vcol = col - 2048;             // h*64 + dd
                const int h = vcol >> 6, dd = vcol & 63;
#pragma unroll
                for (int i = 0; i < 4; ++i) {
                    const int row0 = bm + wm + i * 16 + cr;  // 4-aligned
                    const int b = row0 >> 11, s = row0 & (S_ - 1);
                    const float v0 = acc[i][j][0] + bv;
                    const float v1 = acc[i][j][1] + bv;
                    const float v2 = acc[i][j][2] + bv;
                    const float v3 = acc[i][j][3] + bv;
                    unsigned short* p = (unsigned short*)C2 +
                        ((size_t)((b * H_ + h) * 64 + dd)) * S_ + s;
                    *(uint2*)p = make_uint2(hpack2(v0, v1), hpack2(v2, v3));
                }
            }
        }
    }
}

// ---------------- MFMA flash attention: 8-wave shared-staging variant --------
// Round-2 core (dbuf + permlane + setprio + swizzle) widened to 512 threads:
// 8 waves cover 256 q-rows per block, sharing ONE K/V staging (same 32 KB LDS
// and identical slot placement -> identical numerics). Per-CU staging work and
// barrier-iterations halve (same staged tile feeds 2x compute). New staging
// thread map sr=t>>3, hc=t&7 keeps global reads 128B-coalesced; the resulting
// 2-way LDS write aliasing is free (m136).
__global__ __launch_bounds__(512)
void attn_mfma32(const unsigned short* __restrict__ Qf,
                 const unsigned short* __restrict__ Kfi,
                 const unsigned short* __restrict__ Vt,
                 unsigned short* __restrict__ Cf)
{
    __shared__ uint4 KF[2][512];   // 16 KB: K tile, A-frag order, dbuf
    __shared__ uint4 VF[2][512];   // 16 KB: V^T tile, A-frag order, dbuf

    const int t = threadIdx.x;
    const int i = blockIdx.x;                // [0, 512)
    const int xcd = i & 7, j = i >> 3;       // j in [0,64)
    const int bh = xcd * 8 + (j >> 3);       // 64 (b,h) pairs
    const int qblk = j & 7;                  // 8 q-blocks of 256 rows
    const int b = bh >> 4, h = bh & 15;

    const int w = t >> 6, l = t & 63;        // w in [0,8)
    const int lq = l & 31, h5 = l >> 5;
    const int qrow = qblk * 256 + w * 32 + lq;

    half8 qf[4];
    const unsigned short* qp = Qf + ((size_t)(b * S_ + qrow)) * D_ + h * 64 + h5 * 8;
#pragma unroll
    for (int kc = 0; kc < 4; ++kc) qf[kc] = *(const half8*)(qp + kc * 16);

    floatx16 o0, o1, o2, z16;
#pragma unroll
    for (int r = 0; r < 16; ++r) { o0[r] = 0.f; o1[r] = 0.f; o2[r] = 0.f; z16[r] = 0.f; }

    union { unsigned u[4]; half8 s; } onesf;
    const unsigned ov = (lq == 0) ? 0x3C003C00u : 0u;   // fp16 1.0 pair
    onesf.u[0] = ov; onesf.u[1] = ov; onesf.u[2] = ov; onesf.u[3] = ov;

    // staging: thread t covers (row sr, 8-fp16 chunk hc) — ONE uint4 per
    // operand. Placement identical to the 256-thr version: sc = hc>>1,
    // half = hc&1 -> slot = (sr>>5)*256 + sc*64 + ((sr&31)^(sc<<1)) + half*32.
    const int sr = t >> 3, hc = t & 7, scq = hc >> 1;
    const unsigned short* gK0 = Kfi + ((size_t)(b * S_ + sr)) * D_ + h * 64 + hc * 8;
    const unsigned short* gV0 = Vt + ((size_t)((b * H_ + h) * 64 + sr)) * S_ + hc * 8;
    const int e0 = (sr >> 5) * 256 + scq * 64 + ((sr & 31) ^ (scq << 1)) + (hc & 1) * 32;
    // swizzled read positions per d-chunk kc
    const int lx[4] = { l, l ^ 2, l ^ 4, l ^ 6 };

    // prologue: tile 0 -> buf0; issue tile 1 prefetch
    uint4 ka = *(const uint4*)(gK0);
    uint4 va = *(const uint4*)(gV0);
    KF[0][e0] = ka;
    VF[0][e0] = va;
    {
        const unsigned short* gK = gK0 + (size_t)64 * D_;
        const unsigned short* gV = gV0 + 64;
        ka = *(const uint4*)(gK);
        va = *(const uint4*)(gV);
    }
    __syncthreads();

    for (int kt = 0; kt < 32; ++kt) {
        const int cur = kt & 1;

        // stage tile kt+1 into the other buffer (regs prefetched last iter)
        if (kt < 31) {
            KF[cur ^ 1][e0] = ka;
            VF[cur ^ 1][e0] = va;
        }
        // issue global prefetch for tile kt+2 (consumed next iter; in flight
        // across the lgkm-only barrier below)
        if (kt < 30) {
            const unsigned short* gK = gK0 + (size_t)(kt + 2) * 64 * D_;
            const unsigned short* gV = gV0 + (size_t)(kt + 2) * 64;
            ka = *(const uint4*)(gK);
            va = *(const uint4*)(gV);
        }

        const half8* pKc = (const half8*)KF[cur];
        const half8* pVc = (const half8*)VF[cur];

        __builtin_amdgcn_s_setprio(1);
        floatx16 st0 = __builtin_amdgcn_mfma_f32_32x32x16_f16(pKc[lx[0]],           qf[0], z16, 0, 0, 0);
        floatx16 st1 = __builtin_amdgcn_mfma_f32_32x32x16_f16(pKc[4 * 64 + lx[0]],  qf[0], z16, 0, 0, 0);
#pragma unroll
        for (int kc = 1; kc < 4; ++kc) {
            st0 = __builtin_amdgcn_mfma_f32_32x32x16_f16(pKc[kc * 64 + lx[kc]],       qf[kc], st0, 0, 0, 0);
            st1 = __builtin_amdgcn_mfma_f32_32x32x16_f16(pKc[(4 + kc) * 64 + lx[kc]], qf[kc], st1, 0, 0, 0);
        }
        __builtin_amdgcn_s_setprio(0);

        unsigned pu0[8], pu1[8];
#pragma unroll
        for (int g = 0; g < 8; ++g) {
            pu0[g] = pkrtz(__builtin_amdgcn_exp2f(st0[2 * g]),
                           __builtin_amdgcn_exp2f(st0[2 * g + 1]));
            pu1[g] = pkrtz(__builtin_amdgcn_exp2f(st1[2 * g]),
                           __builtin_amdgcn_exp2f(st1[2 * g + 1]));
        }

        __builtin_amdgcn_s_setprio(1);
#pragma unroll
        for (int kc = 0; kc < 4; ++kc) {
            const unsigned* pus = (kc >> 1) ? pu1 : pu0;
            const int g0 = (kc & 1) * 4;
            const uint2v r02 = __builtin_amdgcn_permlane32_swap(pus[g0 + 0], pus[g0 + 2], false, false);
            const uint2v r13 = __builtin_amdgcn_permlane32_swap(pus[g0 + 1], pus[g0 + 3], false, false);
            union { unsigned u[4]; half8 s; } pf;
            pf.u[0] = r02[0];   // k 0,1 (lo lanes) / 8,9 (hi lanes)
            pf.u[1] = r13[0];   // k 2,3 / 10,11
            pf.u[2] = r02[1];   // k 4,5 / 12,13
            pf.u[3] = r13[1];   // k 6,7 / 14,15
            o0 = __builtin_amdgcn_mfma_f32_32x32x16_f16(pVc[kc * 64 + lx[kc]],       pf.s, o0, 0, 0, 0);
            o1 = __builtin_amdgcn_mfma_f32_32x32x16_f16(pVc[(4 + kc) * 64 + lx[kc]], pf.s, o1, 0, 0, 0);
            o2 = __builtin_amdgcn_mfma_f32_32x32x16_f16(onesf.s,                     pf.s, o2, 0, 0, 0);
        }
        __builtin_amdgcn_s_setprio(0);

        if (kt < 31) barrier_lgkm();
    }

    // l-sum lives in h5=0 lanes' o2[0]; broadcast to h5=1 lanes in one swap
    union { float f; unsigned u; } lc; lc.f = o2[0];
    const uint2v lr = __builtin_amdgcn_permlane32_swap(lc.u, lc.u, false, false);
    union { unsigned u; float f; } ls; ls.u = lr[0];
    const float inv = 1.0f / ls.f;

    const size_t cbase = ((size_t)(b * S_ + qrow)) * D_ + h * 64;
#pragma unroll
    for (int rq = 0; rq < 4; ++rq) {
        const int d0 = rq * 8 + h5 * 4;
        const uint2 y0 = make_uint2(hpack2(o0[4*rq+0] * inv, o0[4*rq+1] * inv),
                                    hpack2(o0[4*rq+2] * inv, o0[4*rq+3] * inv));
        const uint2 y1 = make_uint2(hpack2(o1[4*rq+0] * inv, o1[4*rq+1] * inv),
                                    hpack2(o1[4*rq+2] * inv, o1[4*rq+3] * inv));
        *(uint2*)(Cf + cbase + d0)      = y0;
        *(uint2*)(Cf + cbase + 32 + d0) = y1;
    }
}

extern "C" void kernel_launch(void* const* d_in, const int* in_sizes, int n_in,
                              void* d_out, int out_size, void* d_ws, size_t ws_size,
                              hipStream_t stream) {
    (void)in_sizes; (void)n_in; (void)out_size; (void)ws_size;
    const float* X  = (const float*)d_in[0];
    const float* Wq = (const float*)d_in[1];
    const float* bq = (const float*)d_in[2];
    const float* Wk = (const float*)d_in[3];
    const float* bk = (const float*)d_in[4];
    const float* Wv = (const float*)d_in[5];
    const float* bv = (const float*)d_in[6];
    const float* Wo = (const float*)d_in[7];
    const float* bo = (const float*)d_in[8];
    float* out = (float*)d_out;

    char* ws = (char*)d_ws;
#define OFF(mb) (ws + ((size_t)(mb) << 20))
    unsigned short* Qf    = (unsigned short*)OFF(64);   // 16 MB
    unsigned short* Kfb   = (unsigned short*)OFF(80);   // 16 MB
    unsigned short* Vtb   = (unsigned short*)OFF(96);   // 16 MB (written by gemm1)
    unsigned short* Wqkvf = (unsigned short*)OFF(112);  // 6 MB
    unsigned short* Wof   = (unsigned short*)OFF(118);  // 2 MB
    float*          bqkv  = (float*)OFF(120);           // 12 KB
    float2*         rtab  = (float2*)OFF(121);          // 512 KB RoPE table
    unsigned short* Cf    = (unsigned short*)OFF(0);    // 16 MB
#undef OFF

    conv_all<<<2305, 256, 0, stream>>>(Wq, Wk, Wv, Wo, bq, bk, bv,
                                       Wqkvf, Wof, bqkv, rtab);
    gemm_half<1><<<dim3(64, 24), 256, 0, stream>>>(X, Wqkvf, bqkv,
                                                   Qf, Kfb, Vtb, rtab,
                                                   B_*S_, 3 * D_, D_);
    attn_mfma32<<<512, 512, 0, stream>>>(Qf, Kfb, Vtb, Cf);
    gemm_half<0><<<dim3(64, 8), 256, 0, stream>>>(Cf, Wof, bo, out, nullptr, nullptr,
                                                  nullptr, B_*S_, D_, D_);
}

// Round 13
// 287.574 us; speedup vs baseline: 1.0900x; 1.0900x over previous
//
#include <hip/hip_runtime.h>
#include <cmath>

#define B_ 4
#define S_ 2048
#define D_ 1024
#define H_ 16
#define HD_ 64

typedef __attribute__((ext_vector_type(8))) _Float16 half8;
typedef __attribute__((ext_vector_type(2))) _Float16 half2t;
typedef __attribute__((ext_vector_type(2))) __fp16 fp16x2;
typedef __attribute__((ext_vector_type(4))) float floatx4;
typedef __attribute__((ext_vector_type(16))) float floatx16;
typedef __attribute__((ext_vector_type(2))) unsigned uint2v;

// ---------------- fp16 helpers ----------------
union H2U { unsigned u; half2t h; fp16x2 f; };
__device__ __forceinline__ unsigned hpack2(float a, float b) {   // RNE
    H2U x; x.h[0] = (_Float16)a; x.h[1] = (_Float16)b; return x.u;
}
__device__ __forceinline__ unsigned pkrtz(float a, float b) {    // RTZ, 1 instr
    H2U x; x.f = __builtin_amdgcn_cvt_pkrtz(a, b); return x.u;
}
__device__ __forceinline__ float h_lo(unsigned u) { H2U x; x.u = u; return (float)x.h[0]; }
__device__ __forceinline__ float h_hi(unsigned u) { H2U x; x.u = u; return (float)x.h[1]; }

// barrier that waits LDS ops only — leaves global prefetch loads in flight
__device__ __forceinline__ void barrier_lgkm() {
    asm volatile("s_waitcnt lgkmcnt(0)\n\ts_barrier" ::: "memory");
}

// ---------------- merged prepass: X->fp16 + weights + biases + RoPE table ---
// (round-12 lesson: reading X fp32 directly inside the GEMM costs +24 µs —
// doubled A prefetch regs + 16 hpack2 on the staging critical path, VGPR 60.
// The separate conversion pass is cheaper. REVERTED to round-11 form.)
// Blocks [0,4096): X -> Xf. Blocks [4096,+2048): weights. Block 6144: biases.
// Blocks [6145,6401): RoPE table tab[s][d] = (sin(s*f_d), cos(s*f_d)),
// f_d = exp(-d*ln(10000)/32). Table precomputed here because libm sinf/cosf
// are real calls that force acc spills inside the GEMM (round-9 lesson).
__global__ __launch_bounds__(256)
void conv_all(const float* __restrict__ x, unsigned short* __restrict__ o,
              const float* __restrict__ Wq, const float* __restrict__ Wk,
              const float* __restrict__ Wv, const float* __restrict__ Wo,
              const float* __restrict__ bq, const float* __restrict__ bk,
              const float* __restrict__ bv,
              unsigned short* __restrict__ Wqkvf, unsigned short* __restrict__ Wof,
              float* __restrict__ bqkv, float2* __restrict__ tab)
{
    const int t = threadIdx.x;
    const int bx = blockIdx.x;
    if (bx < 4096) {
        const int i = (bx * 256 + t) * 8;
        const float4 a = *(const float4*)(x + i);
        const float4 b = *(const float4*)(x + i + 4);
        *(uint4*)(o + i) = make_uint4(hpack2(a.x, a.y), hpack2(a.z, a.w),
                                      hpack2(b.x, b.y), hpack2(b.z, b.w));
        return;
    }
    const int bxx = bx - 4096;
    if (bxx < 2048) {
        const int w = bxx >> 9;
        const int i = ((bxx & 511) * 256 + t) * 8;
        const float* src = (w == 0) ? Wq : (w == 1) ? Wk : (w == 2) ? Wv : Wo;
        const float4 a = *(const float4*)(src + i);
        const float4 b = *(const float4*)(src + i + 4);
        const uint4 v = make_uint4(hpack2(a.x, a.y), hpack2(a.z, a.w),
                                   hpack2(b.x, b.y), hpack2(b.z, b.w));
        if (w < 3)
            *(uint4*)(Wqkvf + (size_t)w * 1048576 + i) = v;
        else
            *(uint4*)(Wof + i) = v;
    } else if (bxx == 2048) {
        const int idx = t * 4;
        *(float4*)(bqkv + idx)        = *(const float4*)(bq + idx);
        *(float4*)(bqkv + 1024 + idx) = *(const float4*)(bk + idx);
        *(float4*)(bqkv + 2048 + idx) = *(const float4*)(bv + idx);
    } else {
        const int idx = (bxx - 2049) * 256 + t;   // [0, 65536): s*32 + d
        const int s = idx >> 5, d = idx & 31;
        const float kfreq = 0.28782313662425572f; // ln(10000)/32
        const float fd = expf(-(float)d * kfreq);
        const float tt = (float)s * fd;
        tab[idx] = make_float2(sinf(tt), cosf(tt));
    }
}

// ---------------- GEMM NT, fp16 reg-staged MFMA (round-2 core) --------------
// C[M,N] = A[M,K] * B[N,K]^T + bias. 128x128 tile, BK=32, 256 thr.
// Frag-ordered LDS with k-chunk XOR swizzle; register prefetch of tile k+1.
// MODE 0: fp32 out to C0.
// MODE 1: fused QKV epilogue — RoPE(Q,K) in-register from table (Q->C0,
//   K->C1 scaled 0.125*log2e); V written DIRECTLY TRANSPOSED to C2 =
//   Vt (B,H,64,S): acc[i][j][0..3] are 4 consecutive s at fixed d -> one
//   aligned 8B store.
template<int MODE>
__global__ __launch_bounds__(256, 2)
void gemm_half(const unsigned short* __restrict__ Ap, const unsigned short* __restrict__ Bp,
               const float* __restrict__ bias, void* __restrict__ C0,
               void* __restrict__ C1, void* __restrict__ C2,
               const float2* __restrict__ Tab,
               int M, int N, int K)
{
    __shared__ uint4 ASH[512];
    __shared__ uint4 BSH[512];

    const int tid = threadIdx.x;
    const int bm = blockIdx.x * 128;
    const int bn = blockIdx.y * 128;
    const int w = tid >> 6, l = tid & 63;
    const int wm = (w & 1) * 64, wn = (w >> 1) * 64;

    floatx4 acc[4][4];
#pragma unroll
    for (int i = 0; i < 4; ++i)
#pragma unroll
        for (int j = 0; j < 4; ++j)
#pragma unroll
            for (int r = 0; r < 4; ++r) acc[i][j][r] = 0.f;

    // staging: thread t -> row r = t>>1, k-chunks sc = (t&1)*2 + {0,1} (32B contig)
    const int r0 = tid >> 1, scb = (tid & 1) * 2;
    const size_t ga = (size_t)(bm + r0) * K + scb * 8;
    const size_t gb = (size_t)(bn + r0) * K + scb * 8;
    const int blk = r0 >> 4, r15 = r0 & 15;
    const int p1 = (scb << 4) + r15;
    const int f0a = (blk << 6) + (p1 ^ (scb << 1));              // frag for sck=scb
    const int f0b = (blk << 6) + ((p1 + 16) ^ ((scb + 1) << 1)); // frag for sck=scb+1

    const half8* pA = (const half8*)ASH;
    const half8* pB = (const half8*)BSH;
    const int lg = l ^ ((l >> 4) << 1);      // swizzled position for reads
    const int am = (wm >> 4) * 64 + lg;
    const int bnf = (wn >> 4) * 64 + lg;

    // prefetch k-tile 0
    uint4 vA0 = *(const uint4*)(Ap + ga);
    uint4 vA1 = *(const uint4*)(Ap + ga + 8);
    uint4 vB0 = *(const uint4*)(Bp + gb);
    uint4 vB1 = *(const uint4*)(Bp + gb + 8);

    for (int k0 = 0; k0 < K; k0 += 32) {
        __syncthreads();
        ASH[f0a] = vA0; ASH[f0b] = vA1;
        BSH[f0a] = vB0; BSH[f0b] = vB1;
        __syncthreads();

        const int kn = (k0 + 32 < K) ? k0 + 32 : k0;
        vA0 = *(const uint4*)(Ap + ga + kn);
        vA1 = *(const uint4*)(Ap + ga + kn + 8);
        vB0 = *(const uint4*)(Bp + gb + kn);
        vB1 = *(const uint4*)(Bp + gb + kn + 8);

        half8 a[4];
#pragma unroll
        for (int i = 0; i < 4; ++i) a[i] = pA[am + i * 64];
#pragma unroll
        for (int j = 0; j < 4; ++j) {
            const half8 b = pB[bnf + j * 64];
#pragma unroll
            for (int i = 0; i < 4; ++i)
                acc[i][j] = __builtin_amdgcn_mfma_f32_16x16x32_f16(a[i], b, acc[i][j], 0, 0, 0);
        }
    }

    // epilogue: C/D layout col=lane&15, row=(lane>>4)*4+reg
    const int cr = (l >> 4) << 2;
    const int cc = l & 15;

    if (MODE == 0) {
#pragma unroll
        for (int j = 0; j < 4; ++j) {
            const int col = bn + wn + j * 16 + cc;
            const float bv = bias[col];
#pragma unroll
            for (int i = 0; i < 4; ++i) {
                const int row = bm + wm + i * 16 + cr;
#pragma unroll
                for (int r = 0; r < 4; ++r) {
                    ((float*)C0)[(size_t)(row + r) * N + col] = acc[i][j][r] + bv;
                }
            }
        }
    } else {
        const int reg = bn >> 10;            // 0=Q, 1=K, 2=V (bn 128-aligned)
        if (reg < 2) {
            const float KSs = (reg == 1) ? 0.18033688011112042f : 1.0f;  // 0.125*log2e
            unsigned short* dst0 = (unsigned short*)((reg == 0) ? C0 : C1);
            const int hbase = (bn - (reg << 10)) + wn;   // h*64 within D
#pragma unroll
            for (int j = 0; j < 2; ++j) {
                const int d = j * 16 + cc;               // RoPE dim in [0,32)
                const float b1 = bias[bn + wn + j * 16 + cc];
                const float b2 = bias[bn + wn + j * 16 + cc + 32];
#pragma unroll
                for (int i = 0; i < 4; ++i) {
                    const int row0 = bm + wm + i * 16 + cr;
#pragma unroll
                    for (int r = 0; r < 4; ++r) {
                        const int row = row0 + r;
                        const int s = row & (S_ - 1);
                        const float2 sc2 = Tab[s * 32 + d];
                        const float sn = sc2.x, cs = sc2.y;
                        const float x1 = acc[i][j][r] + b1;
                        const float x2 = acc[i][j + 2][r] + b2;
                        // reference quirk: c=sin part, s=cos part
                        const float o1 = (x1 * sn - x2 * cs) * KSs;
                        const float o2 = (x2 * sn + x1 * cs) * KSs;
                        unsigned short* p = dst0 + (size_t)row * D_ + hbase + d;
                        p[0]  = (unsigned short)(hpack2(o1, o1) & 0xffffu);
                        p[32] = (unsigned short)(hpack2(o2, o2) & 0xffffu);
                    }
                }
            }
        } else {
            // V: write DIRECTLY TRANSPOSED to Vt (B,H,64,S). acc[i][j][0..3]
            // = 4 consecutive s at fixed d -> one aligned 8B store.
#pragma unroll
            for (int j = 0; j < 4; ++j) {
                const int col = bn + wn + j * 16 + cc;
                const float bv = bias[col];
                const int vcol = col - 2048;             // h*64 + dd
                const int h = vcol >> 6, dd = vcol & 63;
#pragma unroll
                for (int i = 0; i < 4; ++i) {
                    const int row0 = bm + wm + i * 16 + cr;  // 4-aligned
                    const int b = row0 >> 11, s = row0 & (S_ - 1);
                    const float v0 = acc[i][j][0] + bv;
                    const float v1 = acc[i][j][1] + bv;
                    const float v2 = acc[i][j][2] + bv;
                    const float v3 = acc[i][j][3] + bv;
                    unsigned short* p = (unsigned short*)C2 +
                        ((size_t)((b * H_ + h) * 64 + dd)) * S_ + s;
                    *(uint2*)p = make_uint2(hpack2(v0, v1), hpack2(v2, v3));
                }
            }
        }
    }
}

// ---------------- MFMA flash attention: 8-wave shared-staging variant --------
// Round-2 core (dbuf + permlane + setprio + swizzle) widened to 512 threads:
// 8 waves cover 256 q-rows per block, sharing ONE K/V staging (same 32 KB LDS
// and identical slot placement -> identical numerics). Per-CU staging work and
// barrier-iterations halve. [round-13: kept to get its counter row; if attn
// >= ~100 µs this variant is null and reverts to 256-thr next round]
__global__ __launch_bounds__(512)
void attn_mfma32(const unsigned short* __restrict__ Qf,
                 const unsigned short* __restrict__ Kfi,
                 const unsigned short* __restrict__ Vt,
                 unsigned short* __restrict__ Cf)
{
    __shared__ uint4 KF[2][512];   // 16 KB: K tile, A-frag order, dbuf
    __shared__ uint4 VF[2][512];   // 16 KB: V^T tile, A-frag order, dbuf

    const int t = threadIdx.x;
    const int i = blockIdx.x;                // [0, 512)
    const int xcd = i & 7, j = i >> 3;       // j in [0,64)
    const int bh = xcd * 8 + (j >> 3);       // 64 (b,h) pairs
    const int qblk = j & 7;                  // 8 q-blocks of 256 rows
    const int b = bh >> 4, h = bh & 15;

    const int w = t >> 6, l = t & 63;        // w in [0,8)
    const int lq = l & 31, h5 = l >> 5;
    const int qrow = qblk * 256 + w * 32 + lq;

    half8 qf[4];
    const unsigned short* qp = Qf + ((size_t)(b * S_ + qrow)) * D_ + h * 64 + h5 * 8;
#pragma unroll
    for (int kc = 0; kc < 4; ++kc) qf[kc] = *(const half8*)(qp + kc * 16);

    floatx16 o0, o1, o2, z16;
#pragma unroll
    for (int r = 0; r < 16; ++r) { o0[r] = 0.f; o1[r] = 0.f; o2[r] = 0.f; z16[r] = 0.f; }

    union { unsigned u[4]; half8 s; } onesf;
    const unsigned ov = (lq == 0) ? 0x3C003C00u : 0u;   // fp16 1.0 pair
    onesf.u[0] = ov; onesf.u[1] = ov; onesf.u[2] = ov; onesf.u[3] = ov;

    // staging: thread t covers (row sr, 8-fp16 chunk hc) — ONE uint4 per
    // operand. Placement identical to the 256-thr version: sc = hc>>1,
    // half = hc&1 -> slot = (sr>>5)*256 + sc*64 + ((sr&31)^(sc<<1)) + half*32.
    const int sr = t >> 3, hc = t & 7, scq = hc >> 1;
    const unsigned short* gK0 = Kfi + ((size_t)(b * S_ + sr)) * D_ + h * 64 + hc * 8;
    const unsigned short* gV0 = Vt + ((size_t)((b * H_ + h) * 64 + sr)) * S_ + hc * 8;
    const int e0 = (sr >> 5) * 256 + scq * 64 + ((sr & 31) ^ (scq << 1)) + (hc & 1) * 32;
    // swizzled read positions per d-chunk kc
    const int lx[4] = { l, l ^ 2, l ^ 4, l ^ 6 };

    // prologue: tile 0 -> buf0; issue tile 1 prefetch
    uint4 ka = *(const uint4*)(gK0);
    uint4 va = *(const uint4*)(gV0);
    KF[0][e0] = ka;
    VF[0][e0] = va;
    {
        const unsigned short* gK = gK0 + (size_t)64 * D_;
        const unsigned short* gV = gV0 + 64;
        ka = *(const uint4*)(gK);
        va = *(const uint4*)(gV);
    }
    __syncthreads();

    for (int kt = 0; kt < 32; ++kt) {
        const int cur = kt & 1;

        // stage tile kt+1 into the other buffer (regs prefetched last iter)
        if (kt < 31) {
            KF[cur ^ 1][e0] = ka;
            VF[cur ^ 1][e0] = va;
        }
        // issue global prefetch for tile kt+2 (consumed next iter; in flight
        // across the lgkm-only barrier below)
        if (kt < 30) {
            const unsigned short* gK = gK0 + (size_t)(kt + 2) * 64 * D_;
            const unsigned short* gV = gV0 + (size_t)(kt + 2) * 64;
            ka = *(const uint4*)(gK);
            va = *(const uint4*)(gV);
        }

        const half8* pKc = (const half8*)KF[cur];
        const half8* pVc = (const half8*)VF[cur];

        __builtin_amdgcn_s_setprio(1);
        floatx16 st0 = __builtin_amdgcn_mfma_f32_32x32x16_f16(pKc[lx[0]],           qf[0], z16, 0, 0, 0);
        floatx16 st1 = __builtin_amdgcn_mfma_f32_32x32x16_f16(pKc[4 * 64 + lx[0]],  qf[0], z16, 0, 0, 0);
#pragma unroll
        for (int kc = 1; kc < 4; ++kc) {
            st0 = __builtin_amdgcn_mfma_f32_32x32x16_f16(pKc[kc * 64 + lx[kc]],       qf[kc], st0, 0, 0, 0);
            st1 = __builtin_amdgcn_mfma_f32_32x32x16_f16(pKc[(4 + kc) * 64 + lx[kc]], qf[kc], st1, 0, 0, 0);
        }
        __builtin_amdgcn_s_setprio(0);

        unsigned pu0[8], pu1[8];
#pragma unroll
        for (int g = 0; g < 8; ++g) {
            pu0[g] = pkrtz(__builtin_amdgcn_exp2f(st0[2 * g]),
                           __builtin_amdgcn_exp2f(st0[2 * g + 1]));
            pu1[g] = pkrtz(__builtin_amdgcn_exp2f(st1[2 * g]),
                           __builtin_amdgcn_exp2f(st1[2 * g + 1]));
        }

        __builtin_amdgcn_s_setprio(1);
#pragma unroll
        for (int kc = 0; kc < 4; ++kc) {
            const unsigned* pus = (kc >> 1) ? pu1 : pu0;
            const int g0 = (kc & 1) * 4;
            const uint2v r02 = __builtin_amdgcn_permlane32_swap(pus[g0 + 0], pus[g0 + 2], false, false);
            const uint2v r13 = __builtin_amdgcn_permlane32_swap(pus[g0 + 1], pus[g0 + 3], false, false);
            union { unsigned u[4]; half8 s; } pf;
            pf.u[0] = r02[0];   // k 0,1 (lo lanes) / 8,9 (hi lanes)
            pf.u[1] = r13[0];   // k 2,3 / 10,11
            pf.u[2] = r02[1];   // k 4,5 / 12,13
            pf.u[3] = r13[1];   // k 6,7 / 14,15
            o0 = __builtin_amdgcn_mfma_f32_32x32x16_f16(pVc[kc * 64 + lx[kc]],       pf.s, o0, 0, 0, 0);
            o1 = __builtin_amdgcn_mfma_f32_32x32x16_f16(pVc[(4 + kc) * 64 + lx[kc]], pf.s, o1, 0, 0, 0);
            o2 = __builtin_amdgcn_mfma_f32_32x32x16_f16(onesf.s,                     pf.s, o2, 0, 0, 0);
        }
        __builtin_amdgcn_s_setprio(0);

        if (kt < 31) barrier_lgkm();
    }

    // l-sum lives in h5=0 lanes' o2[0]; broadcast to h5=1 lanes in one swap
    union { float f; unsigned u; } lc; lc.f = o2[0];
    const uint2v lr = __builtin_amdgcn_permlane32_swap(lc.u, lc.u, false, false);
    union { unsigned u; float f; } ls; ls.u = lr[0];
    const float inv = 1.0f / ls.f;

    const size_t cbase = ((size_t)(b * S_ + qrow)) * D_ + h * 64;
#pragma unroll
    for (int rq = 0; rq < 4; ++rq) {
        const int d0 = rq * 8 + h5 * 4;
        const uint2 y0 = make_uint2(hpack2(o0[4*rq+0] * inv, o0[4*rq+1] * inv),
                                    hpack2(o0[4*rq+2] * inv, o0[4*rq+3] * inv));
        const uint2 y1 = make_uint2(hpack2(o1[4*rq+0] * inv, o1[4*rq+1] * inv),
                                    hpack2(o1[4*rq+2] * inv, o1[4*rq+3] * inv));
        *(uint2*)(Cf + cbase + d0)      = y0;
        *(uint2*)(Cf + cbase + 32 + d0) = y1;
    }
}

extern "C" void kernel_launch(void* const* d_in, const int* in_sizes, int n_in,
                              void* d_out, int out_size, void* d_ws, size_t ws_size,
                              hipStream_t stream) {
    (void)in_sizes; (void)n_in; (void)out_size; (void)ws_size;
    const float* X  = (const float*)d_in[0];
    const float* Wq = (const float*)d_in[1];
    const float* bq = (const float*)d_in[2];
    const float* Wk = (const float*)d_in[3];
    const float* bk = (const float*)d_in[4];
    const float* Wv = (const float*)d_in[5];
    const float* bv = (const float*)d_in[6];
    const float* Wo = (const float*)d_in[7];
    const float* bo = (const float*)d_in[8];
    float* out = (float*)d_out;

    char* ws = (char*)d_ws;
#define OFF(mb) (ws + ((size_t)(mb) << 20))
    unsigned short* Xf    = (unsigned short*)OFF(0);    // 16 MB (dead after QKV GEMM)
    unsigned short* Qf    = (unsigned short*)OFF(64);   // 16 MB
    unsigned short* Kfb   = (unsigned short*)OFF(80);   // 16 MB
    unsigned short* Vtb   = (unsigned short*)OFF(96);   // 16 MB (written by gemm1)
    unsigned short* Wqkvf = (unsigned short*)OFF(112);  // 6 MB
    unsigned short* Wof   = (unsigned short*)OFF(118);  // 2 MB
    float*          bqkv  = (float*)OFF(120);           // 12 KB
    float2*         rtab  = (float2*)OFF(121);          // 512 KB RoPE table
    unsigned short* Cf    = (unsigned short*)OFF(0);    // 16 MB overlay Xf
#undef OFF

    conv_all<<<6401, 256, 0, stream>>>(X, Xf, Wq, Wk, Wv, Wo, bq, bk, bv,
                                       Wqkvf, Wof, bqkv, rtab);
    gemm_half<1><<<dim3(64, 24), 256, 0, stream>>>(Xf, Wqkvf, bqkv,
                                                   Qf, Kfb, Vtb, rtab,
                                                   B_*S_, 3 * D_, D_);
    attn_mfma32<<<512, 512, 0, stream>>>(Qf, Kfb, Vtb, Cf);
    gemm_half<0><<<dim3(64, 8), 256, 0, stream>>>(Cf, Wof, bo, out, nullptr, nullptr,
                                                  nullptr, B_*S_, D_, D_);
}